// Round 7
// baseline (254.360 us; speedup 1.0000x reference)
//
#include <hip/hip_runtime.h>

// CRF log-partition forward, MI355X. 64 blocks (1 per sequence) x 128 threads
// (2 waves). Lane tile: k = tid&3 -> i-chunk [32k,32k+32), g = tid>>2 ->
// j in [4g,4g+4); lane's output tag j == tid (coalesced emissions/writes).
// E tile = 128 VGPRs/lane (64 f2). 64 pk-FMA/lane/step; reduction is
// quad-only (DPP xor1+xor2 + select) -- NO ds_swizzle stage.
// Barrier is lgkmcnt-only inline asm (cross-wave data is LDS-only), so the
// distance-4 emission prefetch stays in flight across steps.
//
// Linear-domain recurrence with exact power-of-2 renormalization:
//   q'_j = exp2(e_j*log2e) * (sum_i q_i E_ij) * 2^(-eS),  eS = exponent(q_0)
//   o    += eS   (integer, exact)
// alpha_j = ln2 * (o + log2 q_j). Final: ln2*(o + log2 sum_j q_j*exp(end_j)).

#define LOG2E 1.4426950408889634f
#define LN2   0.6931471805599453f

// LDS-only workgroup barrier: no vmcnt drain (cross-wave data is LDS only).
#define LDS_BARRIER() asm volatile("s_waitcnt lgkmcnt(0)\n\ts_barrier" ::: "memory")

typedef float f2 __attribute__((ext_vector_type(2)));

template <int CTRL>
__device__ __forceinline__ float dpp_f(float x) {
    return __int_as_float(
        __builtin_amdgcn_mov_dpp(__float_as_int(x), CTRL, 0xF, 0xF, false));
}
template <int CTRL>
__device__ __forceinline__ f2 dpp_f2(f2 x) {
    f2 r;
    r.x = dpp_f<CTRL>(x.x);
    r.y = dpp_f<CTRL>(x.y);
    return r;
}
// quad_perm codes: xor1 = 0xB1, xor2 = 0x4E

__global__ __launch_bounds__(128, 1) void crf_forward(
    const float* __restrict__ emissions,   // [64, 512, 128]
    const float* __restrict__ transitions, // [128, 128]
    const float* __restrict__ start_t,     // [128]
    const float* __restrict__ end_t,       // [128]
    const int*   __restrict__ lengths,     // [64]
    float* __restrict__ out)               // [64]
{
    constexpr int N = 128;
    constexpr int L = 512;
    constexpr int PW = 36;   // padded words per 32-float chunk: disjoint banks
    const int b   = blockIdx.x;
    const int tid = threadIdx.x;   // == this lane's output tag j
    const int g   = tid >> 2;      // j-quad: j in [4g, 4g+4)
    const int k   = tid & 3;       // i-chunk: i in [32k, 32k+32)

    // p_i at word (i>>5)*PW + (i&31); chunk k base = 144k bytes (16B-aligned)
    __shared__ alignas(16) float pbuf[2][4 * PW];
    __shared__ float wsum[2];

    // ---- one-time: 32i x 4j E tile in registers (128 VGPRs).
    // E01[ii] = exp(T[32k+ii][4g+{0,1}]), E23[ii] = exp(T[32k+ii][4g+{2,3}])
    f2 E01[32], E23[32];
    {
        const float* tb = transitions + (size_t)(32 * k) * N + 4 * g;
        #pragma unroll
        for (int ii = 0; ii < 32; ++ii) {
            float4 tv = *reinterpret_cast<const float4*>(tb + (size_t)ii * N);
            E01[ii].x = __builtin_amdgcn_exp2f(tv.x * LOG2E);
            E01[ii].y = __builtin_amdgcn_exp2f(tv.y * LOG2E);
            E23[ii].x = __builtin_amdgcn_exp2f(tv.z * LOG2E);
            E23[ii].y = __builtin_amdgcn_exp2f(tv.w * LOG2E);
        }
    }

    const int len = lengths[b];
    const float* eb = emissions + (size_t)b * L * N;

    // ---- init: q_j = exp2((start_j + e0_j)*log2e), j = tid
    float p = __builtin_amdgcn_exp2f((start_t[tid] + eb[tid]) * LOG2E);
    int o = 0;
    int cur = 0;
    pbuf[0][(tid >> 5) * PW + (tid & 31)] = p;
    LDS_BARRIER();

    auto clampt = [&](int tt) { return tt < len ? tt : len - 1; };
    auto ldE = [&](int tt) { return eb[(size_t)tt * N + tid]; };

    auto STEP = [&](float e_cur) {
        // normalizer source (broadcast b32) + my 32-float chunk (8x b128,
        // four k-groups on disjoint banks via the 36-word pad)
        float p0 = pbuf[cur][0];
        const float4* pv = reinterpret_cast<const float4*>(&pbuf[cur][k * PW]);
        float4 v[8];
        #pragma unroll
        for (int w = 0; w < 8; ++w) v[w] = pv[w];

        float expE = __builtin_amdgcn_exp2f(e_cur * LOG2E);
        int eS = (int)((__float_as_uint(p0) >> 23) & 0xFFu) - 127;
        o += eS;
        float scale = __uint_as_float((unsigned)(127 - eS) << 23);
        float es = expE * scale;   // off the critical tail

        // 64 pk-FMA over the 32i x 4j tile, 4 split accumulator chains
        f2 d01a = {0.f, 0.f}, d01b = {0.f, 0.f};
        f2 d23a = {0.f, 0.f}, d23b = {0.f, 0.f};
        #pragma unroll
        for (int w = 0; w < 8; ++w) {
            #pragma unroll
            for (int e = 0; e < 4; ++e) {
                float pe = (&v[w].x)[e];
                f2 pp = {pe, pe};
                const int ii = w * 4 + e;
                if (ii & 1) {
                    d01b = __builtin_elementwise_fma(pp, E01[ii], d01b);
                    d23b = __builtin_elementwise_fma(pp, E23[ii], d23b);
                } else {
                    d01a = __builtin_elementwise_fma(pp, E01[ii], d01a);
                    d23a = __builtin_elementwise_fma(pp, E23[ii], d23a);
                }
            }
        }
        f2 d01 = d01a + d01b, d23 = d23a + d23b;

        // quad butterfly (DPP) + column select -- no swizzle stage
        d01 += dpp_f2<0xB1>(d01); d23 += dpp_f2<0xB1>(d23);
        d01 += dpp_f2<0x4E>(d01); d23 += dpp_f2<0x4E>(d23);
        f2    dsel = (k & 2) ? d23 : d01;
        float dm   = (k & 1) ? dsel.y : dsel.x;

        p = es * dm;
        cur ^= 1;
        pbuf[cur][(tid >> 5) * PW + (tid & 31)] = p;   // coalesced, 2-way=free
        LDS_BARRIER();
    };

    // ---- main loop: distance-4 emission prefetch, manual 4-way unroll
    float ra = ldE(clampt(1));
    float rb = ldE(clampt(2));
    float rc = ldE(clampt(3));
    float rd = ldE(clampt(4));

    int t = 1;
    while (t < len) {
        STEP(ra); ra = ldE(clampt(t + 4)); ++t; if (t >= len) break;
        STEP(rb); rb = ldE(clampt(t + 4)); ++t; if (t >= len) break;
        STEP(rc); rc = ldE(clampt(t + 4)); ++t; if (t >= len) break;
        STEP(rd); rd = ldE(clampt(t + 4)); ++t;
    }

    // ---- finalize: lane holds its own tag's q in p (no LDS read needed)
    float vend = p * __builtin_amdgcn_exp2f(end_t[tid] * LOG2E);
    #pragma unroll
    for (int m = 1; m < 64; m <<= 1) vend += __shfl_xor(vend, m);
    if ((tid & 63) == 0) wsum[tid >> 6] = vend;
    LDS_BARRIER();
    if (tid == 0)
        out[b] = LN2 * ((float)o + __builtin_amdgcn_logf(wsum[0] + wsum[1]));
}

extern "C" void kernel_launch(void* const* d_in, const int* in_sizes, int n_in,
                              void* d_out, int out_size, void* d_ws, size_t ws_size,
                              hipStream_t stream) {
    const float* emissions   = (const float*)d_in[0];
    const float* transitions = (const float*)d_in[1];
    const float* start_t     = (const float*)d_in[2];
    const float* end_t       = (const float*)d_in[3];
    const int*   lengths     = (const int*)d_in[4];
    float* out = (float*)d_out;

    crf_forward<<<dim3(64), dim3(128), 0, stream>>>(
        emissions, transitions, start_t, end_t, lengths, out);
}

// Round 8
// 223.102 us; speedup vs baseline: 1.1401x; 1.1401x over previous
//
#include <hip/hip_runtime.h>

// CRF log-partition forward, MI355X. 64 blocks (1 per sequence) x 256 threads
// (4 waves). Round-6 structure with one critical fix: the E tile and the LDS
// staging values are REAL registers now. Previous rounds used C arrays with
// address-taken element access ((&v[w].x)[e]) -> SROA bailed -> allocas went
// to scratch; VGPR_Count 52/84 proved E was never in VGPRs. Here: 32 named
// f2 scalars via literal-index macros, float4 components accessed .x/.y/.z/.w.
//
// Lane tile: k = tid&7 -> i-chunk [16k,16k+16), g = tid>>3 -> j in [4g,4g+4).
// Combine: DPP quad butterfly (xor1,xor2) -> select column -> single
// ds_swizzle xor4. Writers k<4 store tag j = 4g+k.
// Barrier: lgkmcnt-only inline asm (cross-wave data is LDS-only) so the
// distance-4 emission prefetch stays in flight across steps.
//
// Linear-domain recurrence with exact power-of-2 renormalization:
//   q'_j = exp2(e_j*log2e) * (sum_i q_i E_ij) * 2^(-eS),  eS = exponent(q_0)
//   o    += eS   (integer, exact)
// alpha_j = ln2 * (o + log2 q_j). Final: ln2*(o + log2 sum_j q_j*exp(end_j)).

#define LOG2E 1.4426950408889634f
#define LN2   0.6931471805599453f

// LDS-only workgroup barrier: no vmcnt drain (cross-wave data is LDS only).
#define LDS_BARRIER() asm volatile("s_waitcnt lgkmcnt(0)\n\ts_barrier" ::: "memory")

typedef float f2 __attribute__((ext_vector_type(2)));

template <int CTRL>
__device__ __forceinline__ float dpp_f(float x) {
    return __int_as_float(
        __builtin_amdgcn_mov_dpp(__float_as_int(x), CTRL, 0xF, 0xF, false));
}
template <int CTRL>
__device__ __forceinline__ f2 dpp_f2(f2 x) {
    f2 r;
    r.x = dpp_f<CTRL>(x.x);
    r.y = dpp_f<CTRL>(x.y);
    return r;
}
// quad_perm codes: xor1 = 0xB1, xor2 = 0x4E
__device__ __forceinline__ float swz_xor4(float x) {
    // BitMode: offset = (xor<<10)|(or<<5)|and ; xor=4, and=0x1F
    return __int_as_float(
        __builtin_amdgcn_ds_swizzle(__float_as_int(x), (4 << 10) | 0x1F));
}

__global__ __launch_bounds__(256, 1) void crf_forward(
    const float* __restrict__ emissions,   // [64, 512, 128]
    const float* __restrict__ transitions, // [128, 128]
    const float* __restrict__ start_t,     // [128]
    const float* __restrict__ end_t,       // [128]
    const int*   __restrict__ lengths,     // [64]
    float* __restrict__ out)               // [64]
{
    constexpr int N = 128;
    constexpr int L = 512;
    constexpr int PW = 20;   // 16 floats + 4 pad per chunk (80 B, 16B-aligned)
    const int b   = blockIdx.x;
    const int tid = threadIdx.x;
    const int g   = tid >> 3;            // j-group: j in [4g, 4g+4)
    const int k   = tid & 7;             // i-chunk: i in [16k, 16k+16)
    const int jw  = 4 * g + (k & 3);     // this lane's output tag (writer iff k<4)

    __shared__ alignas(16) float pbuf[2][8 * PW];
    __shared__ float wsum[2];

    // ---- one-time: 16i x 4j E tile as 32 NAMED f2 registers.
    f2 E01_0,  E01_1,  E01_2,  E01_3,  E01_4,  E01_5,  E01_6,  E01_7;
    f2 E01_8,  E01_9,  E01_10, E01_11, E01_12, E01_13, E01_14, E01_15;
    f2 E23_0,  E23_1,  E23_2,  E23_3,  E23_4,  E23_5,  E23_6,  E23_7;
    f2 E23_8,  E23_9,  E23_10, E23_11, E23_12, E23_13, E23_14, E23_15;
    {
        const float* tb = transitions + (size_t)(16 * k) * N + 4 * g;
#define INIT_E(ii)                                                             \
        {                                                                      \
            float4 tv = *reinterpret_cast<const float4*>(tb + (size_t)(ii) * N); \
            E01_##ii.x = __builtin_amdgcn_exp2f(tv.x * LOG2E);                 \
            E01_##ii.y = __builtin_amdgcn_exp2f(tv.y * LOG2E);                 \
            E23_##ii.x = __builtin_amdgcn_exp2f(tv.z * LOG2E);                 \
            E23_##ii.y = __builtin_amdgcn_exp2f(tv.w * LOG2E);                 \
        }
        INIT_E(0)  INIT_E(1)  INIT_E(2)  INIT_E(3)
        INIT_E(4)  INIT_E(5)  INIT_E(6)  INIT_E(7)
        INIT_E(8)  INIT_E(9)  INIT_E(10) INIT_E(11)
        INIT_E(12) INIT_E(13) INIT_E(14) INIT_E(15)
#undef INIT_E
    }

    const int len = lengths[b];
    const float* eb = emissions + (size_t)b * L * N;

    // ---- init: q_j = exp2((start_j + e0_j)*log2e)
    if (tid < N) {
        float q = __builtin_amdgcn_exp2f((start_t[tid] + eb[tid]) * LOG2E);
        pbuf[0][(tid >> 4) * PW + (tid & 15)] = q;
    }
    int o = 0;
    int cur = 0;
    LDS_BARRIER();

    auto clampt = [&](int tt) { return tt < len ? tt : len - 1; };
    auto ldE = [&](int tt) { return eb[(size_t)tt * N + jw]; };

    auto STEP = [&](float e_cur) {
        // normalizer source + my 16-float chunk (4x b128, disjoint banks)
        float p0 = pbuf[cur][0];
        const float4* pv = reinterpret_cast<const float4*>(&pbuf[cur][k * PW]);
        float4 v0 = pv[0], v1 = pv[1], v2 = pv[2], v3 = pv[3];

        float expE = __builtin_amdgcn_exp2f(e_cur * LOG2E);
        int eS = (int)((__float_as_uint(p0) >> 23) & 0xFFu) - 127;
        o += eS;
        float scale = __uint_as_float((unsigned)(127 - eS) << 23);
        float es = expE * scale;   // off the critical tail

        // 32 pk-FMA over the 16i x 4j tile, alternating A/B chains
        f2 d01a = {0.f, 0.f}, d01b = {0.f, 0.f};
        f2 d23a = {0.f, 0.f}, d23b = {0.f, 0.f};
#define ACC_A(vc, ii)                                                          \
        {                                                                      \
            f2 pp = {vc, vc};                                                  \
            d01a = __builtin_elementwise_fma(pp, E01_##ii, d01a);              \
            d23a = __builtin_elementwise_fma(pp, E23_##ii, d23a);              \
        }
#define ACC_B(vc, ii)                                                          \
        {                                                                      \
            f2 pp = {vc, vc};                                                  \
            d01b = __builtin_elementwise_fma(pp, E01_##ii, d01b);              \
            d23b = __builtin_elementwise_fma(pp, E23_##ii, d23b);              \
        }
        ACC_A(v0.x, 0)  ACC_B(v0.y, 1)  ACC_A(v0.z, 2)  ACC_B(v0.w, 3)
        ACC_A(v1.x, 4)  ACC_B(v1.y, 5)  ACC_A(v1.z, 6)  ACC_B(v1.w, 7)
        ACC_A(v2.x, 8)  ACC_B(v2.y, 9)  ACC_A(v2.z, 10) ACC_B(v2.w, 11)
        ACC_A(v3.x, 12) ACC_B(v3.y, 13) ACC_A(v3.z, 14) ACC_B(v3.w, 15)
#undef ACC_A
#undef ACC_B
        f2 d01 = d01a + d01b, d23 = d23a + d23b;

        // quad butterfly (DPP) -> select column -> single xor4 swizzle
        d01 += dpp_f2<0xB1>(d01); d23 += dpp_f2<0xB1>(d23);
        d01 += dpp_f2<0x4E>(d01); d23 += dpp_f2<0x4E>(d23);
        f2    dsel = (k & 2) ? d23 : d01;
        float dm   = (k & 1) ? dsel.y : dsel.x;
        dm += swz_xor4(dm);

        float pn = es * dm;
        cur ^= 1;
        if (k < 4) pbuf[cur][(jw >> 4) * PW + (jw & 15)] = pn;
        LDS_BARRIER();
    };

    // ---- main loop: distance-4 emission prefetch, manual 4-way unroll
    float ra = ldE(clampt(1));
    float rb = ldE(clampt(2));
    float rc = ldE(clampt(3));
    float rd = ldE(clampt(4));

    int t = 1;
    while (t < len) {
        STEP(ra); ra = ldE(clampt(t + 4)); ++t; if (t >= len) break;
        STEP(rb); rb = ldE(clampt(t + 4)); ++t; if (t >= len) break;
        STEP(rc); rc = ldE(clampt(t + 4)); ++t; if (t >= len) break;
        STEP(rd); rd = ldE(clampt(t + 4)); ++t;
    }

    // ---- finalize: out[b] = ln2 * (o + log2(sum_j q_j * exp2(end_j*log2e)))
    if (tid < N) {
        float q = pbuf[cur][(tid >> 4) * PW + (tid & 15)];
        float vend = q * __builtin_amdgcn_exp2f(end_t[tid] * LOG2E);
        #pragma unroll
        for (int m = 1; m < 64; m <<= 1) vend += __shfl_xor(vend, m);
        if ((tid & 63) == 0) wsum[tid >> 6] = vend;
    }
    LDS_BARRIER();
    if (tid == 0)
        out[b] = LN2 * ((float)o + __builtin_amdgcn_logf(wsum[0] + wsum[1]));
}

extern "C" void kernel_launch(void* const* d_in, const int* in_sizes, int n_in,
                              void* d_out, int out_size, void* d_ws, size_t ws_size,
                              hipStream_t stream) {
    const float* emissions   = (const float*)d_in[0];
    const float* transitions = (const float*)d_in[1];
    const float* start_t     = (const float*)d_in[2];
    const float* end_t       = (const float*)d_in[3];
    const int*   lengths     = (const int*)d_in[4];
    float* out = (float*)d_out;

    crf_forward<<<dim3(64), dim3(256), 0, stream>>>(
        emissions, transitions, start_t, end_t, lengths, out);
}

// Round 9
// 203.784 us; speedup vs baseline: 1.2482x; 1.0948x over previous
//
#include <hip/hip_runtime.h>

// CRF log-partition forward, MI355X. 64 blocks (1 per sequence) x 256 threads
// (4 waves). Round-8 structure + ONE change: amdgpu_waves_per_eu(1,1).
// Rounds 5-8 all showed VGPR_Count (52/84/184) BELOW the E-tile footprint
// while FETCH stayed ~4MB -> the allocator was parking E in AGPRs (default
// occupancy heuristic targets ~8 waves/EU -> <=64 arch VGPRs) and paying
// v_accvgpr_read copies every step. Real occupancy is exactly 1 wave/EU
// (64 blocks x 4 waves on 256 CUs), so pinning waves-per-eu to 1,1 frees the
// full 256-VGPR arch budget at zero occupancy cost.
//
// Lane tile: k = tid&7 -> i-chunk [16k,16k+16), g = tid>>3 -> j in [4g,4g+4).
// Combine: DPP quad butterfly (xor1,xor2) -> select column -> single
// ds_swizzle xor4. Writers k<4 store tag j = 4g+k.
// Barrier: lgkmcnt-only inline asm (cross-wave data is LDS-only) so the
// distance-4 emission prefetch stays in flight across steps.
//
// Linear-domain recurrence with exact power-of-2 renormalization:
//   q'_j = exp2(e_j*log2e) * (sum_i q_i E_ij) * 2^(-eS),  eS = exponent(q_0)
//   o    += eS   (integer, exact)
// alpha_j = ln2 * (o + log2 q_j). Final: ln2*(o + log2 sum_j q_j*exp(end_j)).

#define LOG2E 1.4426950408889634f
#define LN2   0.6931471805599453f

// LDS-only workgroup barrier: no vmcnt drain (cross-wave data is LDS only).
#define LDS_BARRIER() asm volatile("s_waitcnt lgkmcnt(0)\n\ts_barrier" ::: "memory")

typedef float f2 __attribute__((ext_vector_type(2)));

template <int CTRL>
__device__ __forceinline__ float dpp_f(float x) {
    return __int_as_float(
        __builtin_amdgcn_mov_dpp(__float_as_int(x), CTRL, 0xF, 0xF, false));
}
template <int CTRL>
__device__ __forceinline__ f2 dpp_f2(f2 x) {
    f2 r;
    r.x = dpp_f<CTRL>(x.x);
    r.y = dpp_f<CTRL>(x.y);
    return r;
}
// quad_perm codes: xor1 = 0xB1, xor2 = 0x4E
__device__ __forceinline__ float swz_xor4(float x) {
    // BitMode: offset = (xor<<10)|(or<<5)|and ; xor=4, and=0x1F
    return __int_as_float(
        __builtin_amdgcn_ds_swizzle(__float_as_int(x), (4 << 10) | 0x1F));
}

__global__ __launch_bounds__(256)
__attribute__((amdgpu_waves_per_eu(1, 1)))
void crf_forward(
    const float* __restrict__ emissions,   // [64, 512, 128]
    const float* __restrict__ transitions, // [128, 128]
    const float* __restrict__ start_t,     // [128]
    const float* __restrict__ end_t,       // [128]
    const int*   __restrict__ lengths,     // [64]
    float* __restrict__ out)               // [64]
{
    constexpr int N = 128;
    constexpr int L = 512;
    constexpr int PW = 20;   // 16 floats + 4 pad per chunk (80 B, 16B-aligned)
    const int b   = blockIdx.x;
    const int tid = threadIdx.x;
    const int g   = tid >> 3;            // j-group: j in [4g, 4g+4)
    const int k   = tid & 7;             // i-chunk: i in [16k, 16k+16)
    const int jw  = 4 * g + (k & 3);     // this lane's output tag (writer iff k<4)

    __shared__ alignas(16) float pbuf[2][8 * PW];
    __shared__ float wsum[2];

    // ---- one-time: 16i x 4j E tile as 32 NAMED f2 registers.
    f2 E01_0,  E01_1,  E01_2,  E01_3,  E01_4,  E01_5,  E01_6,  E01_7;
    f2 E01_8,  E01_9,  E01_10, E01_11, E01_12, E01_13, E01_14, E01_15;
    f2 E23_0,  E23_1,  E23_2,  E23_3,  E23_4,  E23_5,  E23_6,  E23_7;
    f2 E23_8,  E23_9,  E23_10, E23_11, E23_12, E23_13, E23_14, E23_15;
    {
        const float* tb = transitions + (size_t)(16 * k) * N + 4 * g;
#define INIT_E(ii)                                                             \
        {                                                                      \
            float4 tv = *reinterpret_cast<const float4*>(tb + (size_t)(ii) * N); \
            E01_##ii.x = __builtin_amdgcn_exp2f(tv.x * LOG2E);                 \
            E01_##ii.y = __builtin_amdgcn_exp2f(tv.y * LOG2E);                 \
            E23_##ii.x = __builtin_amdgcn_exp2f(tv.z * LOG2E);                 \
            E23_##ii.y = __builtin_amdgcn_exp2f(tv.w * LOG2E);                 \
        }
        INIT_E(0)  INIT_E(1)  INIT_E(2)  INIT_E(3)
        INIT_E(4)  INIT_E(5)  INIT_E(6)  INIT_E(7)
        INIT_E(8)  INIT_E(9)  INIT_E(10) INIT_E(11)
        INIT_E(12) INIT_E(13) INIT_E(14) INIT_E(15)
#undef INIT_E
    }

    const int len = lengths[b];
    const float* eb = emissions + (size_t)b * L * N;

    // ---- init: q_j = exp2((start_j + e0_j)*log2e)
    if (tid < N) {
        float q = __builtin_amdgcn_exp2f((start_t[tid] + eb[tid]) * LOG2E);
        pbuf[0][(tid >> 4) * PW + (tid & 15)] = q;
    }
    int o = 0;
    int cur = 0;
    LDS_BARRIER();

    auto clampt = [&](int tt) { return tt < len ? tt : len - 1; };
    auto ldE = [&](int tt) { return eb[(size_t)tt * N + jw]; };

    auto STEP = [&](float e_cur) {
        // normalizer source + my 16-float chunk (4x b128, disjoint banks)
        float p0 = pbuf[cur][0];
        const float4* pv = reinterpret_cast<const float4*>(&pbuf[cur][k * PW]);
        float4 v0 = pv[0], v1 = pv[1], v2 = pv[2], v3 = pv[3];

        float expE = __builtin_amdgcn_exp2f(e_cur * LOG2E);
        int eS = (int)((__float_as_uint(p0) >> 23) & 0xFFu) - 127;
        o += eS;
        float scale = __uint_as_float((unsigned)(127 - eS) << 23);
        float es = expE * scale;   // off the critical tail

        // 32 pk-FMA over the 16i x 4j tile, alternating A/B chains
        f2 d01a = {0.f, 0.f}, d01b = {0.f, 0.f};
        f2 d23a = {0.f, 0.f}, d23b = {0.f, 0.f};
#define ACC_A(vc, ii)                                                          \
        {                                                                      \
            f2 pp = {vc, vc};                                                  \
            d01a = __builtin_elementwise_fma(pp, E01_##ii, d01a);              \
            d23a = __builtin_elementwise_fma(pp, E23_##ii, d23a);              \
        }
#define ACC_B(vc, ii)                                                          \
        {                                                                      \
            f2 pp = {vc, vc};                                                  \
            d01b = __builtin_elementwise_fma(pp, E01_##ii, d01b);              \
            d23b = __builtin_elementwise_fma(pp, E23_##ii, d23b);              \
        }
        ACC_A(v0.x, 0)  ACC_B(v0.y, 1)  ACC_A(v0.z, 2)  ACC_B(v0.w, 3)
        ACC_A(v1.x, 4)  ACC_B(v1.y, 5)  ACC_A(v1.z, 6)  ACC_B(v1.w, 7)
        ACC_A(v2.x, 8)  ACC_B(v2.y, 9)  ACC_A(v2.z, 10) ACC_B(v2.w, 11)
        ACC_A(v3.x, 12) ACC_B(v3.y, 13) ACC_A(v3.z, 14) ACC_B(v3.w, 15)
#undef ACC_A
#undef ACC_B
        f2 d01 = d01a + d01b, d23 = d23a + d23b;

        // quad butterfly (DPP) -> select column -> single xor4 swizzle
        d01 += dpp_f2<0xB1>(d01); d23 += dpp_f2<0xB1>(d23);
        d01 += dpp_f2<0x4E>(d01); d23 += dpp_f2<0x4E>(d23);
        f2    dsel = (k & 2) ? d23 : d01;
        float dm   = (k & 1) ? dsel.y : dsel.x;
        dm += swz_xor4(dm);

        float pn = es * dm;
        cur ^= 1;
        if (k < 4) pbuf[cur][(jw >> 4) * PW + (jw & 15)] = pn;
        LDS_BARRIER();
    };

    // ---- main loop: distance-4 emission prefetch, manual 4-way unroll
    float ra = ldE(clampt(1));
    float rb = ldE(clampt(2));
    float rc = ldE(clampt(3));
    float rd = ldE(clampt(4));

    int t = 1;
    while (t < len) {
        STEP(ra); ra = ldE(clampt(t + 4)); ++t; if (t >= len) break;
        STEP(rb); rb = ldE(clampt(t + 4)); ++t; if (t >= len) break;
        STEP(rc); rc = ldE(clampt(t + 4)); ++t; if (t >= len) break;
        STEP(rd); rd = ldE(clampt(t + 4)); ++t;
    }

    // ---- finalize: out[b] = ln2 * (o + log2(sum_j q_j * exp2(end_j*log2e)))
    if (tid < N) {
        float q = pbuf[cur][(tid >> 4) * PW + (tid & 15)];
        float vend = q * __builtin_amdgcn_exp2f(end_t[tid] * LOG2E);
        #pragma unroll
        for (int m = 1; m < 64; m <<= 1) vend += __shfl_xor(vend, m);
        if ((tid & 63) == 0) wsum[tid >> 6] = vend;
    }
    LDS_BARRIER();
    if (tid == 0)
        out[b] = LN2 * ((float)o + __builtin_amdgcn_logf(wsum[0] + wsum[1]));
}

extern "C" void kernel_launch(void* const* d_in, const int* in_sizes, int n_in,
                              void* d_out, int out_size, void* d_ws, size_t ws_size,
                              hipStream_t stream) {
    const float* emissions   = (const float*)d_in[0];
    const float* transitions = (const float*)d_in[1];
    const float* start_t     = (const float*)d_in[2];
    const float* end_t       = (const float*)d_in[3];
    const int*   lengths     = (const int*)d_in[4];
    float* out = (float*)d_out;

    crf_forward<<<dim3(64), dim3(256), 0, stream>>>(
        emissions, transitions, start_t, end_t, lengths, out);
}